// Round 5
// baseline (581.049 us; speedup 1.0000x reference)
//
#include <hip/hip_runtime.h>
#include <hip/hip_fp16.h>

#define F_IN 48
#define F_HID 64
#define GSH 7            // nodes per bucket = 128
#define GSZ 128
#define CAPSH 12         // edges capacity per bucket = 4096 (avg 2048, +45 sigma)
#define CAP 4096

__device__ __forceinline__ bool detect64(const int* __restrict__ e) {
    // int64 edge_index: odd words are high halves of values < 2^31 -> all zero.
    // int32: odd words are src[1],src[3],src[5],src[7] (random node ids).
    return ((e[1] | e[3] | e[5] | e[7]) == 0);
}

__device__ __forceinline__ int load_src(const int* e, int i, int E, bool is64) {
    return e[is64 ? (long)2 * i : (long)i];
}
__device__ __forceinline__ int load_dst(const int* e, int i, int E, bool is64) {
    return e[is64 ? (long)2 * (E + i) : (long)(E + i)];
}

// ---- pass A: direct atomic bucket-scatter (782 counters; tails L2-resident) ----
__global__ __launch_bounds__(256) void passA(const int* __restrict__ e,
                                             int* __restrict__ bcnt,
                                             int* __restrict__ ebuf, int E) {
    bool is64 = detect64(e);
    int i0 = (blockIdx.x * 256 + threadIdx.x) * 4;
#pragma unroll
    for (int r = 0; r < 4; ++r) {
        int i = i0 + r;
        if (i < E) {
            int s = load_src(e, i, E, is64);
            int d = load_dst(e, i, E, is64);
            int b = d >> GSH;
            int pos = atomicAdd(&bcnt[b], 1);
            if (pos < CAP)
                ebuf[((long)b << CAPSH) + pos] = s | ((d & (GSZ - 1)) << 17);
        }
    }
}

// ---- pass B: per-bucket node sort -> deg/rowStart/dinv/srcSorted + y16 rows ----
__global__ __launch_bounds__(256) void passB(const int* __restrict__ ebuf,
                                             const int* __restrict__ bcnt,
                                             const float* __restrict__ x,
                                             int* __restrict__ rowStart,
                                             int* __restrict__ deg,
                                             float* __restrict__ dinv,
                                             int* __restrict__ srcSorted,
                                             __half* __restrict__ y, int N) {
    __shared__ int cnt[GSZ], base[GSZ], cur[GSZ];
    __shared__ float ldinv[GSZ];
    int b = blockIdx.x, t = threadIdx.x;
    int m = min(bcnt[b], CAP);
    const int* eb = ebuf + ((long)b << CAPSH);
    if (t < GSZ) cnt[t] = 0;
    __syncthreads();
    for (int i = t; i < m; i += 256) atomicAdd(&cnt[eb[i] >> 17], 1);
    __syncthreads();
    if (t < GSZ) base[t] = cnt[t];
    __syncthreads();
    for (int o = 1; o < GSZ; o <<= 1) {
        int v = (t < GSZ && t >= o) ? base[t - o] : 0;
        __syncthreads();
        if (t < GSZ) base[t] += v;
        __syncthreads();
    }
    if (t < GSZ) {
        int ex = base[t] - cnt[t];  // exclusive
        cur[t] = ex;
        float di = rsqrtf((float)cnt[t] + 1.0f);
        ldinv[t] = di;
        int node = (b << GSH) + t;
        if (node < N) {
            rowStart[node] = (b << CAPSH) + ex;  // index into padded srcSorted
            deg[node] = cnt[t];
            dinv[node] = di;
        }
    }
    __syncthreads();
    for (int i = t; i < m; i += 256) {
        int pk = eb[i];
        int p = atomicAdd(&cur[pk >> 17], 1);
        srcSorted[((long)b << CAPSH) + p] = pk & 0x1FFFF;
    }
    // fused prep_y: y16[n][k] = half(dinv[n]*x[n][k]), rows padded to 64
    int nodeBase = b << GSH;
    for (int q = t; q < GSZ * 64; q += 256) {
        int nl = q >> 6, k = q & 63;
        int node = nodeBase + nl;
        if (node < N) {
            float v = (k < F_IN) ? ldinv[nl] * x[(long)node * F_IN + k] : 0.0f;
            y[((long)node << 6) + k] = __float2half(v);
        }
    }
}

// ---- fused: half2 dual-edge CSR aggregation + GEMM1 + relu + W2 -> g2 ----
__global__ __launch_bounds__(256) void fused1(const __half* __restrict__ y,
                                              const float* __restrict__ W1,
                                              const float* __restrict__ b1,
                                              const float* __restrict__ W2,
                                              const float* __restrict__ dinv,
                                              const int* __restrict__ rowStart,
                                              const int* __restrict__ deg,
                                              const int* __restrict__ srcSorted,
                                              float* __restrict__ g2, int N) {
    int lane = threadIdx.x & 63;
    int sub = lane >> 5;   // which edge of the pair this half-wave handles
    int fl = lane & 31;    // feature-pair index (features 2*fl, 2*fl+1)
    int node = blockIdx.x * 4 + (threadIdx.x >> 6);
    if (node >= N) return;
    int rs = rowStart[node];
    int dn = deg[node];
    int dn2 = dn + 1;  // + self-loop: y[node] is exactly the self term
    // preload row indices: slot i = (i<dn) ? srcSorted[rs+i] : node(self)
    int myIdx = node;
    if (lane < dn) myIdx = srcSorted[rs + lane];  // one coalesced load
    int lim = dn2 < 64 ? dn2 : 64;
    const __half2* yp = (const __half2*)y;
    float ax = 0.0f, ay = 0.0f;
    int j = 0;
    for (; j + 16 <= lim; j += 16) {  // 8 gathers in flight = 16 edges
        int i0 = __shfl(myIdx, j + 0 + sub, 64);
        int i1 = __shfl(myIdx, j + 2 + sub, 64);
        int i2 = __shfl(myIdx, j + 4 + sub, 64);
        int i3 = __shfl(myIdx, j + 6 + sub, 64);
        int i4 = __shfl(myIdx, j + 8 + sub, 64);
        int i5 = __shfl(myIdx, j + 10 + sub, 64);
        int i6 = __shfl(myIdx, j + 12 + sub, 64);
        int i7 = __shfl(myIdx, j + 14 + sub, 64);
        __half2 v0 = yp[((long)i0 << 5) + fl];
        __half2 v1 = yp[((long)i1 << 5) + fl];
        __half2 v2 = yp[((long)i2 << 5) + fl];
        __half2 v3 = yp[((long)i3 << 5) + fl];
        __half2 v4 = yp[((long)i4 << 5) + fl];
        __half2 v5 = yp[((long)i5 << 5) + fl];
        __half2 v6 = yp[((long)i6 << 5) + fl];
        __half2 v7 = yp[((long)i7 << 5) + fl];
        float2 f0 = __half22float2(v0), f1 = __half22float2(v1);
        float2 f2 = __half22float2(v2), f3 = __half22float2(v3);
        float2 f4 = __half22float2(v4), f5 = __half22float2(v5);
        float2 f6 = __half22float2(v6), f7 = __half22float2(v7);
        ax += ((f0.x + f1.x) + (f2.x + f3.x)) + ((f4.x + f5.x) + (f6.x + f7.x));
        ay += ((f0.y + f1.y) + (f2.y + f3.y)) + ((f4.y + f5.y) + (f6.y + f7.y));
    }
    for (; j + 2 <= lim; j += 2) {
        int i0 = __shfl(myIdx, j + sub, 64);
        float2 f0 = __half22float2(yp[((long)i0 << 5) + fl]);
        ax += f0.x;
        ay += f0.y;
    }
    if (j < lim) {  // odd leftover: sub 0 only
        int i0 = __shfl(myIdx, j, 64);
        float2 f0 = __half22float2(yp[((long)i0 << 5) + fl]);
        if (sub == 0) { ax += f0.x; ay += f0.y; }
    }
    for (int s2 = 64; s2 < dn2; ++s2) {  // deg>63: astronomically rare
        int s = (s2 < dn) ? srcSorted[rs + s2] : node;
        float2 f0 = __half22float2(yp[((long)s << 5) + fl]);
        if (sub == 0) { ax += f0.x; ay += f0.y; }
    }
    // combine the two half-waves
    ax += __shfl(ax, lane ^ 32, 64);
    ay += __shfl(ay, lane ^ 32, 64);
    float di = dinv[node];
    ax *= di;
    ay *= di;  // lane holds v[2*fl], v[2*fl+1]
    // h[f] = relu(sum_k v[k]*W1[k][f] + b1[f]), f = lane
    float h = b1[lane];
#pragma unroll
    for (int k = 0; k < F_IN; k += 2) {
        h = fmaf(__shfl(ax, k >> 1, 64), W1[k * F_HID + lane], h);
        h = fmaf(__shfl(ay, k >> 1, 64), W1[(k + 1) * F_HID + lane], h);
    }
    h = fmaxf(h, 0.0f);
    float2 w2 = ((const float2*)W2)[lane];
    float t0 = h * w2.x, t1 = h * w2.y;
#pragma unroll
    for (int off = 32; off > 0; off >>= 1) {
        t0 += __shfl_down(t0, off, 64);
        t1 += __shfl_down(t1, off, 64);
    }
    if (lane == 0) ((float2*)g2)[node] = make_float2(di * t0, di * t1);
}

// ---- layer-2 CSR aggregation (g2 is L2-resident) + final epilogue ----
__global__ void agg2(const int* __restrict__ rowStart, const int* __restrict__ deg,
                     const int* __restrict__ srcSorted, const float* __restrict__ g2,
                     const float* __restrict__ dinv, const float* __restrict__ b2,
                     float* __restrict__ out, int N) {
    int n = blockIdx.x * blockDim.x + threadIdx.x;
    if (n >= N) return;
    const float2* g2v = (const float2*)g2;
    int rs = rowStart[n], dn = deg[n];
    float a0 = 0.0f, a1 = 0.0f;
    int j = 0;
    for (; j + 8 <= dn; j += 8) {
        int s0 = srcSorted[rs + j + 0], s1 = srcSorted[rs + j + 1];
        int s2 = srcSorted[rs + j + 2], s3 = srcSorted[rs + j + 3];
        int s4 = srcSorted[rs + j + 4], s5 = srcSorted[rs + j + 5];
        int s6 = srcSorted[rs + j + 6], s7 = srcSorted[rs + j + 7];
        float2 v0 = g2v[s0], v1 = g2v[s1], v2 = g2v[s2], v3 = g2v[s3];
        float2 v4 = g2v[s4], v5 = g2v[s5], v6 = g2v[s6], v7 = g2v[s7];
        a0 += ((v0.x + v1.x) + (v2.x + v3.x)) + ((v4.x + v5.x) + (v6.x + v7.x));
        a1 += ((v0.y + v1.y) + (v2.y + v3.y)) + ((v4.y + v5.y) + (v6.y + v7.y));
    }
    for (; j < dn; ++j) {
        float2 v0 = g2v[srcSorted[rs + j]];
        a0 += v0.x;
        a1 += v0.y;
    }
    float2 self = g2v[n];
    float di = dinv[n];
    out[2 * n + 0] = di * (a0 + self.x) + b2[0];
    out[2 * n + 1] = di * (a1 + self.y) + b2[1];
}

extern "C" void kernel_launch(void* const* d_in, const int* in_sizes, int n_in,
                              void* d_out, int out_size, void* d_ws, size_t ws_size,
                              hipStream_t stream) {
    const float* x  = (const float*)d_in[0];
    const int* eidx = (const int*)d_in[1];
    const float* W1 = (const float*)d_in[2];
    const float* b1 = (const float*)d_in[3];
    const float* W2 = (const float*)d_in[4];
    const float* b2 = (const float*)d_in[5];
    float* out = (float*)d_out;

    int N = in_sizes[0] / F_IN;   // 100000
    int E = in_sizes[1] / 2;      // 1600000
    int B = (N + GSZ - 1) >> GSH; // 782 buckets

    char* ws = (char*)d_ws;
    int*    bcnt      = (int*)ws;      ws += (size_t)B * 4;
    int*    deg       = (int*)ws;      ws += (size_t)N * 4;
    int*    rowStart  = (int*)ws;      ws += (size_t)N * 4;
    float*  dinv      = (float*)ws;    ws += (size_t)N * 4;
    float*  g2        = (float*)ws;    ws += (size_t)N * 2 * 4;
    ws = (char*)(((size_t)ws + 255) & ~(size_t)255);
    int*    ebuf      = (int*)ws;      ws += (size_t)B * CAP * 4;   // 12.8 MB
    int*    srcSorted = (int*)ws;      ws += (size_t)B * CAP * 4;   // 12.8 MB
    __half* y16       = (__half*)ws;   ws += (size_t)N * 64 * 2;    // 12.8 MB

    hipMemsetAsync(bcnt, 0, (size_t)B * sizeof(int), stream);

    passA<<<(E / 4 + 255) / 256, 256, 0, stream>>>(eidx, bcnt, ebuf, E);
    passB<<<B, 256, 0, stream>>>(ebuf, bcnt, x, rowStart, deg, dinv, srcSorted,
                                 y16, N);
    fused1<<<(N + 3) / 4, 256, 0, stream>>>(y16, W1, b1, W2, dinv, rowStart, deg,
                                            srcSorted, g2, N);
    agg2<<<(N + 255) / 256, 256, 0, stream>>>(rowStart, deg, srcSorted, g2, dinv,
                                              b2, out, N);
}

// Round 6
// 218.743 us; speedup vs baseline: 2.6563x; 2.6563x over previous
//
#include <hip/hip_runtime.h>
#include <hip/hip_fp16.h>

#define F_IN 48
#define F_HID 64
#define GSH 7            // nodes per bucket = 128
#define GSZ 128
#define MAXB 1024        // supports N <= 131072 (pack: src in 17 bits, g in 7)
#define CAPSH 12         // edges capacity per bucket = 4096 (avg 2048, +45 sigma)
#define CAP 4096
#define CHUNK 4096       // edges per passA block (16 per thread)

__device__ __forceinline__ bool detect64(const int* __restrict__ e) {
    // int64 edge_index: odd words are high halves of values < 2^31 -> all zero.
    // int32: odd words are src[1],src[3],src[5],src[7] (random node ids).
    return ((e[1] | e[3] | e[5] | e[7]) == 0);
}

__device__ __forceinline__ int load_src(const int* e, int i, int E, bool is64) {
    return e[is64 ? (long)2 * i : (long)i];
}
__device__ __forceinline__ int load_dst(const int* e, int i, int E, bool is64) {
    return e[is64 ? (long)2 * (E + i) : (long)(E + i)];
}

// ---- pass A: chunk reservation. LDS histogram -> ONE global atomic per
// (block,bucket) -> scatter into reserved contiguous runs. Avoids the
// 2048-serial-atomics-per-counter trap of direct scatter (R5: 378us). ----
__global__ __launch_bounds__(256) void passA(const int* __restrict__ e,
                                             int* __restrict__ bcnt,
                                             int* __restrict__ ebuf, int E) {
    __shared__ int lcnt[MAXB], lbase[MAXB];
    bool is64 = detect64(e);
    int base = blockIdx.x * CHUNK;
    for (int t = threadIdx.x; t < MAXB; t += 256) lcnt[t] = 0;
    __syncthreads();
    int pk[16], bk[16];
    int cnt = 0;
#pragma unroll
    for (int r = 0; r < 16; ++r) {
        int i = base + r * 256 + threadIdx.x;
        if (i < E) {
            int s = load_src(e, i, E, is64);
            int d = load_dst(e, i, E, is64);
            pk[r] = s | ((d & (GSZ - 1)) << 17);
            bk[r] = d >> GSH;
            atomicAdd(&lcnt[bk[r]], 1);
            cnt = r + 1;
        }
    }
    __syncthreads();
    for (int t = threadIdx.x; t < MAXB; t += 256) {
        int c = lcnt[t];
        lbase[t] = c ? atomicAdd(&bcnt[t], c) : 0;
    }
    __syncthreads();
    for (int t = threadIdx.x; t < MAXB; t += 256) lcnt[t] = 0;
    __syncthreads();
    for (int r = 0; r < cnt; ++r) {
        int b = bk[r];
        int off = atomicAdd(&lcnt[b], 1);
        int pos = lbase[b] + off;
        if (pos < CAP) ebuf[((long)b << CAPSH) + pos] = pk[r];
    }
}

// ---- pass B: per-bucket node sort -> deg/rowStart/dinv/srcSorted + y16 rows ----
__global__ __launch_bounds__(256) void passB(const int* __restrict__ ebuf,
                                             const int* __restrict__ bcnt,
                                             const float* __restrict__ x,
                                             int* __restrict__ rowStart,
                                             int* __restrict__ deg,
                                             float* __restrict__ dinv,
                                             int* __restrict__ srcSorted,
                                             __half* __restrict__ y, int N) {
    __shared__ int cnt[GSZ], base[GSZ], cur[GSZ];
    __shared__ float ldinv[GSZ];
    int b = blockIdx.x, t = threadIdx.x;
    int m = min(bcnt[b], CAP);
    const int* eb = ebuf + ((long)b << CAPSH);
    if (t < GSZ) cnt[t] = 0;
    __syncthreads();
    for (int i = t; i < m; i += 256) atomicAdd(&cnt[eb[i] >> 17], 1);
    __syncthreads();
    if (t < GSZ) base[t] = cnt[t];
    __syncthreads();
    for (int o = 1; o < GSZ; o <<= 1) {
        int v = (t < GSZ && t >= o) ? base[t - o] : 0;
        __syncthreads();
        if (t < GSZ) base[t] += v;
        __syncthreads();
    }
    if (t < GSZ) {
        int ex = base[t] - cnt[t];  // exclusive
        cur[t] = ex;
        float di = rsqrtf((float)cnt[t] + 1.0f);
        ldinv[t] = di;
        int node = (b << GSH) + t;
        if (node < N) {
            rowStart[node] = (b << CAPSH) + ex;  // index into padded srcSorted
            deg[node] = cnt[t];
            dinv[node] = di;
        }
    }
    __syncthreads();
    for (int i = t; i < m; i += 256) {
        int pk = eb[i];
        int p = atomicAdd(&cur[pk >> 17], 1);
        srcSorted[((long)b << CAPSH) + p] = pk & 0x1FFFF;
    }
    // fused prep_y: y16[n][k] = half(dinv[n]*x[n][k]), rows padded to 64
    int nodeBase = b << GSH;
    for (int q = t; q < GSZ * 64; q += 256) {
        int nl = q >> 6, k = q & 63;
        int node = nodeBase + nl;
        if (node < N) {
            float v = (k < F_IN) ? ldinv[nl] * x[(long)node * F_IN + k] : 0.0f;
            y[((long)node << 6) + k] = __float2half(v);
        }
    }
}

// ---- fused: half2 dual-edge CSR aggregation + GEMM1 + relu + W2 -> g2 ----
__global__ __launch_bounds__(256) void fused1(const __half* __restrict__ y,
                                              const float* __restrict__ W1,
                                              const float* __restrict__ b1,
                                              const float* __restrict__ W2,
                                              const float* __restrict__ dinv,
                                              const int* __restrict__ rowStart,
                                              const int* __restrict__ deg,
                                              const int* __restrict__ srcSorted,
                                              float* __restrict__ g2, int N) {
    int lane = threadIdx.x & 63;
    int sub = lane >> 5;   // which edge of the pair this half-wave handles
    int fl = lane & 31;    // feature-pair index (features 2*fl, 2*fl+1)
    int node = blockIdx.x * 4 + (threadIdx.x >> 6);
    if (node >= N) return;
    int rs = rowStart[node];
    int dn = deg[node];
    int dn2 = dn + 1;  // + self-loop: y[node] is exactly the self term
    // preload row indices: slot i = (i<dn) ? srcSorted[rs+i] : node(self)
    int myIdx = node;
    if (lane < dn) myIdx = srcSorted[rs + lane];  // one coalesced load
    int lim = dn2 < 64 ? dn2 : 64;
    const __half2* yp = (const __half2*)y;
    float ax = 0.0f, ay = 0.0f;
    int j = 0;
    for (; j + 16 <= lim; j += 16) {  // 8 gathers in flight = 16 edges
        int i0 = __shfl(myIdx, j + 0 + sub, 64);
        int i1 = __shfl(myIdx, j + 2 + sub, 64);
        int i2 = __shfl(myIdx, j + 4 + sub, 64);
        int i3 = __shfl(myIdx, j + 6 + sub, 64);
        int i4 = __shfl(myIdx, j + 8 + sub, 64);
        int i5 = __shfl(myIdx, j + 10 + sub, 64);
        int i6 = __shfl(myIdx, j + 12 + sub, 64);
        int i7 = __shfl(myIdx, j + 14 + sub, 64);
        __half2 v0 = yp[((long)i0 << 5) + fl];
        __half2 v1 = yp[((long)i1 << 5) + fl];
        __half2 v2 = yp[((long)i2 << 5) + fl];
        __half2 v3 = yp[((long)i3 << 5) + fl];
        __half2 v4 = yp[((long)i4 << 5) + fl];
        __half2 v5 = yp[((long)i5 << 5) + fl];
        __half2 v6 = yp[((long)i6 << 5) + fl];
        __half2 v7 = yp[((long)i7 << 5) + fl];
        float2 f0 = __half22float2(v0), f1 = __half22float2(v1);
        float2 f2 = __half22float2(v2), f3 = __half22float2(v3);
        float2 f4 = __half22float2(v4), f5 = __half22float2(v5);
        float2 f6 = __half22float2(v6), f7 = __half22float2(v7);
        ax += ((f0.x + f1.x) + (f2.x + f3.x)) + ((f4.x + f5.x) + (f6.x + f7.x));
        ay += ((f0.y + f1.y) + (f2.y + f3.y)) + ((f4.y + f5.y) + (f6.y + f7.y));
    }
    for (; j + 2 <= lim; j += 2) {
        int i0 = __shfl(myIdx, j + sub, 64);
        float2 f0 = __half22float2(yp[((long)i0 << 5) + fl]);
        ax += f0.x;
        ay += f0.y;
    }
    if (j < lim) {  // odd leftover: sub 0 only
        int i0 = __shfl(myIdx, j, 64);
        float2 f0 = __half22float2(yp[((long)i0 << 5) + fl]);
        if (sub == 0) { ax += f0.x; ay += f0.y; }
    }
    for (int s2 = 64; s2 < dn2; ++s2) {  // deg>63: astronomically rare
        int s = (s2 < dn) ? srcSorted[rs + s2] : node;
        float2 f0 = __half22float2(yp[((long)s << 5) + fl]);
        if (sub == 0) { ax += f0.x; ay += f0.y; }
    }
    // combine the two half-waves
    ax += __shfl(ax, lane ^ 32, 64);
    ay += __shfl(ay, lane ^ 32, 64);
    float di = dinv[node];
    ax *= di;
    ay *= di;  // lane holds v[2*fl], v[2*fl+1]
    // h[f] = relu(sum_k v[k]*W1[k][f] + b1[f]), f = lane
    float h = b1[lane];
#pragma unroll
    for (int k = 0; k < F_IN; k += 2) {
        h = fmaf(__shfl(ax, k >> 1, 64), W1[k * F_HID + lane], h);
        h = fmaf(__shfl(ay, k >> 1, 64), W1[(k + 1) * F_HID + lane], h);
    }
    h = fmaxf(h, 0.0f);
    float2 w2 = ((const float2*)W2)[lane];
    float t0 = h * w2.x, t1 = h * w2.y;
#pragma unroll
    for (int off = 32; off > 0; off >>= 1) {
        t0 += __shfl_down(t0, off, 64);
        t1 += __shfl_down(t1, off, 64);
    }
    if (lane == 0) ((float2*)g2)[node] = make_float2(di * t0, di * t1);
}

// ---- layer-2 CSR aggregation (g2 is L2-resident) + final epilogue ----
__global__ void agg2(const int* __restrict__ rowStart, const int* __restrict__ deg,
                     const int* __restrict__ srcSorted, const float* __restrict__ g2,
                     const float* __restrict__ dinv, const float* __restrict__ b2,
                     float* __restrict__ out, int N) {
    int n = blockIdx.x * blockDim.x + threadIdx.x;
    if (n >= N) return;
    const float2* g2v = (const float2*)g2;
    int rs = rowStart[n], dn = deg[n];
    float a0 = 0.0f, a1 = 0.0f;
    int j = 0;
    for (; j + 8 <= dn; j += 8) {
        int s0 = srcSorted[rs + j + 0], s1 = srcSorted[rs + j + 1];
        int s2 = srcSorted[rs + j + 2], s3 = srcSorted[rs + j + 3];
        int s4 = srcSorted[rs + j + 4], s5 = srcSorted[rs + j + 5];
        int s6 = srcSorted[rs + j + 6], s7 = srcSorted[rs + j + 7];
        float2 v0 = g2v[s0], v1 = g2v[s1], v2 = g2v[s2], v3 = g2v[s3];
        float2 v4 = g2v[s4], v5 = g2v[s5], v6 = g2v[s6], v7 = g2v[s7];
        a0 += ((v0.x + v1.x) + (v2.x + v3.x)) + ((v4.x + v5.x) + (v6.x + v7.x));
        a1 += ((v0.y + v1.y) + (v2.y + v3.y)) + ((v4.y + v5.y) + (v6.y + v7.y));
    }
    for (; j < dn; ++j) {
        float2 v0 = g2v[srcSorted[rs + j]];
        a0 += v0.x;
        a1 += v0.y;
    }
    float2 self = g2v[n];
    float di = dinv[n];
    out[2 * n + 0] = di * (a0 + self.x) + b2[0];
    out[2 * n + 1] = di * (a1 + self.y) + b2[1];
}

extern "C" void kernel_launch(void* const* d_in, const int* in_sizes, int n_in,
                              void* d_out, int out_size, void* d_ws, size_t ws_size,
                              hipStream_t stream) {
    const float* x  = (const float*)d_in[0];
    const int* eidx = (const int*)d_in[1];
    const float* W1 = (const float*)d_in[2];
    const float* b1 = (const float*)d_in[3];
    const float* W2 = (const float*)d_in[4];
    const float* b2 = (const float*)d_in[5];
    float* out = (float*)d_out;

    int N = in_sizes[0] / F_IN;   // 100000
    int E = in_sizes[1] / 2;      // 1600000
    int B = (N + GSZ - 1) >> GSH; // 782 buckets (<= MAXB)

    char* ws = (char*)d_ws;
    int*    bcnt      = (int*)ws;      ws += MAXB * 4;
    int*    deg       = (int*)ws;      ws += (size_t)N * 4;
    int*    rowStart  = (int*)ws;      ws += (size_t)N * 4;
    float*  dinv      = (float*)ws;    ws += (size_t)N * 4;
    float*  g2        = (float*)ws;    ws += (size_t)N * 2 * 4;
    ws = (char*)(((size_t)ws + 255) & ~(size_t)255);
    int*    ebuf      = (int*)ws;      ws += (size_t)MAXB * CAP * 4;
    int*    srcSorted = (int*)ws;      ws += (size_t)MAXB * CAP * 4;
    __half* y16       = (__half*)ws;   ws += (size_t)N * 64 * 2;

    hipMemsetAsync(bcnt, 0, MAXB * sizeof(int), stream);

    passA<<<(E + CHUNK - 1) / CHUNK, 256, 0, stream>>>(eidx, bcnt, ebuf, E);
    passB<<<B, 256, 0, stream>>>(ebuf, bcnt, x, rowStart, deg, dinv, srcSorted,
                                 y16, N);
    fused1<<<(N + 3) / 4, 256, 0, stream>>>(y16, W1, b1, W2, dinv, rowStart, deg,
                                            srcSorted, g2, N);
    agg2<<<(N + 255) / 256, 256, 0, stream>>>(rowStart, deg, srcSorted, g2, dinv,
                                              b2, out, N);
}

// Round 7
// 185.579 us; speedup vs baseline: 3.1310x; 1.1787x over previous
//
#include <hip/hip_runtime.h>
#include <hip/hip_fp16.h>

#define F_IN 48
#define F_HID 64
#define GSH 7            // nodes per bucket = 128
#define GSZ 128
#define MAXB 1024        // supports N <= 131072 (pack: src in 17 bits, g in 7)
#define CAPSH 12         // edges capacity per bucket = 4096 (avg 2048, +45 sigma)
#define CAP 4096
#define CHUNK 4096       // edges per passA block (16 per thread)

__device__ __forceinline__ bool detect64(const int* __restrict__ e) {
    return ((e[1] | e[3] | e[5] | e[7]) == 0);
}
__device__ __forceinline__ int load_src(const int* e, int i, int E, bool is64) {
    return e[is64 ? (long)2 * i : (long)i];
}
__device__ __forceinline__ int load_dst(const int* e, int i, int E, bool is64) {
    return e[is64 ? (long)2 * (E + i) : (long)(E + i)];
}
__device__ __forceinline__ float rdlane(float v, int l) {
    return __uint_as_float(__builtin_amdgcn_readlane(__float_as_uint(v), l));
}

// ---- pass A: chunk reservation (one global atomic per block,bucket) ----
__global__ __launch_bounds__(256) void passA(const int* __restrict__ e,
                                             int* __restrict__ bcnt,
                                             int* __restrict__ ebuf, int E) {
    __shared__ int lcnt[MAXB], lbase[MAXB];
    bool is64 = detect64(e);
    int base = blockIdx.x * CHUNK;
    for (int t = threadIdx.x; t < MAXB; t += 256) lcnt[t] = 0;
    __syncthreads();
    int pk[16], bk[16];
    int cnt = 0;
#pragma unroll
    for (int r = 0; r < 16; ++r) {
        int i = base + r * 256 + threadIdx.x;
        if (i < E) {
            int s = load_src(e, i, E, is64);
            int d = load_dst(e, i, E, is64);
            pk[r] = s | ((d & (GSZ - 1)) << 17);
            bk[r] = d >> GSH;
            atomicAdd(&lcnt[bk[r]], 1);
            cnt = r + 1;
        }
    }
    __syncthreads();
    for (int t = threadIdx.x; t < MAXB; t += 256) {
        int c = lcnt[t];
        lbase[t] = c ? atomicAdd(&bcnt[t], c) : 0;
    }
    __syncthreads();
    for (int t = threadIdx.x; t < MAXB; t += 256) lcnt[t] = 0;
    __syncthreads();
    for (int r = 0; r < cnt; ++r) {
        int b = bk[r];
        int off = atomicAdd(&lcnt[b], 1);
        int pos = lbase[b] + off;
        if (pos < CAP) ebuf[((long)b << CAPSH) + pos] = pk[r];
    }
}

// ---- pass B: per-bucket node sort -> deg/rowStart/dinv/srcSorted + y16 rows ----
__global__ __launch_bounds__(256) void passB(const int* __restrict__ ebuf,
                                             const int* __restrict__ bcnt,
                                             const float* __restrict__ x,
                                             int* __restrict__ rowStart,
                                             int* __restrict__ deg,
                                             float* __restrict__ dinv,
                                             int* __restrict__ srcSorted,
                                             __half* __restrict__ y, int N) {
    __shared__ int cnt[GSZ], base[GSZ], cur[GSZ];
    __shared__ float ldinv[GSZ];
    int b = blockIdx.x, t = threadIdx.x;
    int m = min(bcnt[b], CAP);
    const int* eb = ebuf + ((long)b << CAPSH);
    if (t < GSZ) cnt[t] = 0;
    __syncthreads();
    for (int i = t; i < m; i += 256) atomicAdd(&cnt[eb[i] >> 17], 1);
    __syncthreads();
    if (t < GSZ) base[t] = cnt[t];
    __syncthreads();
    for (int o = 1; o < GSZ; o <<= 1) {
        int v = (t < GSZ && t >= o) ? base[t - o] : 0;
        __syncthreads();
        if (t < GSZ) base[t] += v;
        __syncthreads();
    }
    if (t < GSZ) {
        int ex = base[t] - cnt[t];
        cur[t] = ex;
        float di = rsqrtf((float)cnt[t] + 1.0f);
        ldinv[t] = di;
        int node = (b << GSH) + t;
        if (node < N) {
            rowStart[node] = (b << CAPSH) + ex;
            deg[node] = cnt[t];
            dinv[node] = di;
        }
    }
    __syncthreads();
    for (int i = t; i < m; i += 256) {
        int pk = eb[i];
        int p = atomicAdd(&cur[pk >> 17], 1);
        srcSorted[((long)b << CAPSH) + p] = pk & 0x1FFFF;
    }
    int nodeBase = b << GSH;
    for (int q = t; q < GSZ * 64; q += 256) {
        int nl = q >> 6, k = q & 63;
        int node = nodeBase + nl;
        if (node < N) {
            float v = (k < F_IN) ? ldinv[nl] * x[(long)node * F_IN + k] : 0.0f;
            y[((long)node << 6) + k] = __float2half(v);
        }
    }
}

// ---- fused: 4 nodes/wave, 48 gathers in flight, readlane GEMM epilogue ----
__global__ __launch_bounds__(256) void fused1(const __half* __restrict__ y,
                                              const float* __restrict__ W1,
                                              const float* __restrict__ b1,
                                              const float* __restrict__ W2,
                                              const float* __restrict__ dinv,
                                              const int* __restrict__ rowStart,
                                              const int* __restrict__ deg,
                                              const int* __restrict__ srcSorted,
                                              float* __restrict__ g2, int N) {
    const int lane = threadIdx.x & 63;
    const int sub = lane >> 5;     // which edge of a slot-pair this half-wave takes
    const int fl = lane & 31;      // half2 index within a row (64 halves = 32 half2)
    const int base = blockIdx.x * 16 + (threadIdx.x >> 6) * 4;
    const __half2* yp = (const __half2*)y;

    int n0 = base, n1 = base + 1, n2 = base + 2, n3 = base + 3;
    int dn0 = (n0 < N) ? deg[n0] : -1;
    int dn1 = (n1 < N) ? deg[n1] : -1;
    int dn2_ = (n2 < N) ? deg[n2] : -1;
    int dn3 = (n3 < N) ? deg[n3] : -1;
    int rs0 = (n0 < N) ? rowStart[n0] : 0;
    int rs1 = (n1 < N) ? rowStart[n1] : 0;
    int rs2 = (n2 < N) ? rowStart[n2] : 0;
    int rs3 = (n3 < N) ? rowStart[n3] : 0;

    // slot map per lane: [0,dn)=edges, dn=self, rest=zero row N
    int idx0 = N, idx1 = N, idx2 = N, idx3 = N;
    if (lane < dn0) idx0 = srcSorted[rs0 + lane]; else if (lane == dn0) idx0 = n0;
    if (lane < dn1) idx1 = srcSorted[rs1 + lane]; else if (lane == dn1) idx1 = n1;
    if (lane < dn2_) idx2 = srcSorted[rs2 + lane]; else if (lane == dn2_) idx2 = n2;
    if (lane < dn3) idx3 = srcSorted[rs3 + lane]; else if (lane == dn3) idx3 = n3;

    float ax0 = 0, ay0 = 0, ax1 = 0, ay1 = 0;
    float ax2 = 0, ay2 = 0, ax3 = 0, ay3 = 0;

    auto step = [&](int p) {
        int sA = 2 * p + sub;
        int i0 = __shfl(idx0, sA, 64);
        int i1 = __shfl(idx1, sA, 64);
        int i2 = __shfl(idx2, sA, 64);
        int i3 = __shfl(idx3, sA, 64);
        float2 f0 = __half22float2(yp[((long)i0 << 5) + fl]);
        float2 f1 = __half22float2(yp[((long)i1 << 5) + fl]);
        float2 f2 = __half22float2(yp[((long)i2 << 5) + fl]);
        float2 f3 = __half22float2(yp[((long)i3 << 5) + fl]);
        ax0 += f0.x; ay0 += f0.y;
        ax1 += f1.x; ay1 += f1.y;
        ax2 += f2.x; ay2 += f2.y;
        ax3 += f3.x; ay3 += f3.y;
    };
#pragma unroll
    for (int p = 0; p < 12; ++p) step(p);   // 48 independent gathers in flight
    int maxSlot = max(max(dn0, dn1), max(dn2_, dn3)) + 1;
    for (int p = 12; p < 32 && 2 * p < maxSlot; ++p) step(p);  // rare
    if (maxSlot > 64) {  // astronomically rare
        for (int s = 64; s < maxSlot; ++s) {
            if (sub == 0) {
                if (s <= dn0) { float2 f = __half22float2(yp[((long)((s < dn0) ? srcSorted[rs0 + s] : n0) << 5) + fl]); ax0 += f.x; ay0 += f.y; }
                if (s <= dn1) { float2 f = __half22float2(yp[((long)((s < dn1) ? srcSorted[rs1 + s] : n1) << 5) + fl]); ax1 += f.x; ay1 += f.y; }
                if (s <= dn2_) { float2 f = __half22float2(yp[((long)((s < dn2_) ? srcSorted[rs2 + s] : n2) << 5) + fl]); ax2 += f.x; ay2 += f.y; }
                if (s <= dn3) { float2 f = __half22float2(yp[((long)((s < dn3) ? srcSorted[rs3 + s] : n3) << 5) + fl]); ax3 += f.x; ay3 += f.y; }
            }
        }
    }

    // combine half-waves: lanes then hold v[2*fl], v[2*fl+1]
    ax0 += __shfl(ax0, lane ^ 32, 64); ay0 += __shfl(ay0, lane ^ 32, 64);
    ax1 += __shfl(ax1, lane ^ 32, 64); ay1 += __shfl(ay1, lane ^ 32, 64);
    ax2 += __shfl(ax2, lane ^ 32, 64); ay2 += __shfl(ay2, lane ^ 32, 64);
    ax3 += __shfl(ax3, lane ^ 32, 64); ay3 += __shfl(ay3, lane ^ 32, 64);
    float di0 = (n0 < N) ? dinv[n0] : 0.0f;
    float di1 = (n1 < N) ? dinv[n1] : 0.0f;
    float di2 = (n2 < N) ? dinv[n2] : 0.0f;
    float di3 = (n3 < N) ? dinv[n3] : 0.0f;
    ax0 *= di0; ay0 *= di0; ax1 *= di1; ay1 *= di1;
    ax2 *= di2; ay2 *= di2; ax3 *= di3; ay3 *= di3;

    // h_i[f] = relu(sum_k v_i[k]*W1[k][f] + b1[f]); W1 loads shared by 4 nodes,
    // broadcasts via v_readlane -> SGPR (off the LDS pipe)
    float h0 = b1[lane], h1 = h0, h2 = h0, h3 = h0;
#pragma unroll
    for (int k = 0; k < F_IN; k += 2) {
        float wA = W1[k * F_HID + lane];
        float wB = W1[(k + 1) * F_HID + lane];
        const int q = k >> 1;
        h0 = fmaf(rdlane(ax0, q), wA, h0); h0 = fmaf(rdlane(ay0, q), wB, h0);
        h1 = fmaf(rdlane(ax1, q), wA, h1); h1 = fmaf(rdlane(ay1, q), wB, h1);
        h2 = fmaf(rdlane(ax2, q), wA, h2); h2 = fmaf(rdlane(ay2, q), wB, h2);
        h3 = fmaf(rdlane(ax3, q), wA, h3); h3 = fmaf(rdlane(ay3, q), wB, h3);
    }
    h0 = fmaxf(h0, 0.0f); h1 = fmaxf(h1, 0.0f);
    h2 = fmaxf(h2, 0.0f); h3 = fmaxf(h3, 0.0f);

    float2 w2 = ((const float2*)W2)[lane];
    float t00 = h0 * w2.x, t01 = h0 * w2.y;
    float t10 = h1 * w2.x, t11 = h1 * w2.y;
    float t20 = h2 * w2.x, t21 = h2 * w2.y;
    float t30 = h3 * w2.x, t31 = h3 * w2.y;
#pragma unroll
    for (int off = 32; off > 0; off >>= 1) {
        t00 += __shfl_down(t00, off, 64); t01 += __shfl_down(t01, off, 64);
        t10 += __shfl_down(t10, off, 64); t11 += __shfl_down(t11, off, 64);
        t20 += __shfl_down(t20, off, 64); t21 += __shfl_down(t21, off, 64);
        t30 += __shfl_down(t30, off, 64); t31 += __shfl_down(t31, off, 64);
    }
    if (lane == 0) {
        float2* g2v = (float2*)g2;
        if (n0 < N) g2v[n0] = make_float2(di0 * t00, di0 * t01);
        if (n1 < N) g2v[n1] = make_float2(di1 * t10, di1 * t11);
        if (n2 < N) g2v[n2] = make_float2(di2 * t20, di2 * t21);
        if (n3 < N) g2v[n3] = make_float2(di3 * t30, di3 * t31);
    }
}

// ---- layer-2 aggregation: 16 lanes per node, coalesced index reads ----
__global__ __launch_bounds__(256) void agg2(const int* __restrict__ rowStart,
                                            const int* __restrict__ deg,
                                            const int* __restrict__ srcSorted,
                                            const float* __restrict__ g2,
                                            const float* __restrict__ dinv,
                                            const float* __restrict__ b2,
                                            float* __restrict__ out, int N) {
    int gid = blockIdx.x * 256 + threadIdx.x;
    int node = gid >> 4, l16 = gid & 15;
    if (node >= N) return;
    const float2* g2v = (const float2*)g2;
    int rs = rowStart[node], dn = deg[node];
    float a0 = 0.0f, a1 = 0.0f;
    for (int j = l16; j < dn; j += 16) {
        float2 v = g2v[srcSorted[rs + j]];
        a0 += v.x;
        a1 += v.y;
    }
#pragma unroll
    for (int m = 1; m < 16; m <<= 1) {
        a0 += __shfl_xor(a0, m, 64);
        a1 += __shfl_xor(a1, m, 64);
    }
    if (l16 == 0) {
        float2 self = g2v[node];
        float di = dinv[node];
        out[2 * node + 0] = di * (a0 + self.x) + b2[0];
        out[2 * node + 1] = di * (a1 + self.y) + b2[1];
    }
}

extern "C" void kernel_launch(void* const* d_in, const int* in_sizes, int n_in,
                              void* d_out, int out_size, void* d_ws, size_t ws_size,
                              hipStream_t stream) {
    const float* x  = (const float*)d_in[0];
    const int* eidx = (const int*)d_in[1];
    const float* W1 = (const float*)d_in[2];
    const float* b1 = (const float*)d_in[3];
    const float* W2 = (const float*)d_in[4];
    const float* b2 = (const float*)d_in[5];
    float* out = (float*)d_out;

    int N = in_sizes[0] / F_IN;   // 100000
    int E = in_sizes[1] / 2;      // 1600000
    int B = (N + GSZ - 1) >> GSH; // 782 buckets (<= MAXB)

    char* ws = (char*)d_ws;
    int*    bcnt      = (int*)ws;      ws += MAXB * 4;
    int*    deg       = (int*)ws;      ws += (size_t)N * 4;
    int*    rowStart  = (int*)ws;      ws += (size_t)N * 4;
    float*  dinv      = (float*)ws;    ws += (size_t)N * 4;
    float*  g2        = (float*)ws;    ws += (size_t)N * 2 * 4;
    ws = (char*)(((size_t)ws + 255) & ~(size_t)255);
    int*    ebuf      = (int*)ws;      ws += (size_t)MAXB * CAP * 4;
    int*    srcSorted = (int*)ws;      ws += (size_t)MAXB * CAP * 4;
    __half* y16       = (__half*)ws;   ws += (size_t)(N + 1) * 64 * 2;  // +zero row

    hipMemsetAsync(bcnt, 0, MAXB * sizeof(int), stream);
    hipMemsetAsync(y16 + (size_t)N * 64, 0, 64 * sizeof(__half), stream);  // row N = 0

    passA<<<(E + CHUNK - 1) / CHUNK, 256, 0, stream>>>(eidx, bcnt, ebuf, E);
    passB<<<B, 256, 0, stream>>>(ebuf, bcnt, x, rowStart, deg, dinv, srcSorted,
                                 y16, N);
    fused1<<<(N + 15) / 16, 256, 0, stream>>>(y16, W1, b1, W2, dinv, rowStart, deg,
                                              srcSorted, g2, N);
    agg2<<<(N * 16 + 255) / 256, 256, 0, stream>>>(rowStart, deg, srcSorted, g2,
                                                   dinv, b2, out, N);
}

// Round 8
// 170.527 us; speedup vs baseline: 3.4074x; 1.0883x over previous
//
#include <hip/hip_runtime.h>
#include <hip/hip_fp16.h>

#define F_IN 48
#define F_HID 64
#define GSH 7            // nodes per bucket = 128
#define GSZ 128
#define MAXB 1024        // supports N <= 131072 (pack: src in 17 bits, g in 7)
#define CAPSH 12         // edges capacity per bucket = 4096 (avg 2048, +45 sigma)
#define CAP 4096
#define CHUNK 4096       // edges per passA block (16 per thread)

__device__ __forceinline__ bool detect64(const int* __restrict__ e) {
    return ((e[1] | e[3] | e[5] | e[7]) == 0);
}
__device__ __forceinline__ int load_src(const int* e, int i, int E, bool is64) {
    return e[is64 ? (long)2 * i : (long)i];
}
__device__ __forceinline__ int load_dst(const int* e, int i, int E, bool is64) {
    return e[is64 ? (long)2 * (E + i) : (long)(E + i)];
}
__device__ __forceinline__ float rdlane(float v, int l) {
    return __uint_as_float(__builtin_amdgcn_readlane(__float_as_uint(v), l));
}

// ---- pass A: chunk reservation. First-pass LDS atomicAdd RETURNS each edge's
// within-block rank -> no second LDS-atomic pass needed. int4 edge loads. ----
__global__ __launch_bounds__(256) void passA(const int* __restrict__ e,
                                             int* __restrict__ bcnt,
                                             int* __restrict__ ebuf, int E, int B) {
    __shared__ int lcnt[MAXB], lbase[MAXB];
    bool is64 = detect64(e);
    bool vec = ((E & 3) == 0);
    int base = blockIdx.x * CHUNK;
    for (int t = threadIdx.x; t < B; t += 256) lcnt[t] = 0;
    __syncthreads();
    int pk[16], bk[16], rk[16];
#pragma unroll
    for (int g = 0; g < 4; ++g) {
        int i = base + (((g << 8) + (int)threadIdx.x) << 2);
        int r = g * 4;
        if (vec && i + 3 < E) {
            int4 s4, d4;
            if (is64) {
                const int4* p = (const int4*)(e + (size_t)2 * i);
                int4 a = p[0], bb = p[1];
                s4 = make_int4(a.x, a.z, bb.x, bb.z);
                const int4* q = (const int4*)(e + (size_t)2 * E + (size_t)2 * i);
                int4 c = q[0], dd = q[1];
                d4 = make_int4(c.x, c.z, dd.x, dd.z);
            } else {
                s4 = *(const int4*)(e + i);
                d4 = *(const int4*)(e + E + i);
            }
            int ss[4] = {s4.x, s4.y, s4.z, s4.w};
            int dv[4] = {d4.x, d4.y, d4.z, d4.w};
#pragma unroll
            for (int u = 0; u < 4; ++u) {
                pk[r + u] = ss[u] | ((dv[u] & (GSZ - 1)) << 17);
                bk[r + u] = dv[u] >> GSH;
                rk[r + u] = atomicAdd(&lcnt[bk[r + u]], 1);
            }
        } else {
#pragma unroll
            for (int u = 0; u < 4; ++u) {
                int ii = i + u;
                if (ii < E) {
                    int s = load_src(e, ii, E, is64);
                    int d = load_dst(e, ii, E, is64);
                    pk[r + u] = s | ((d & (GSZ - 1)) << 17);
                    bk[r + u] = d >> GSH;
                    rk[r + u] = atomicAdd(&lcnt[bk[r + u]], 1);
                } else {
                    bk[r + u] = -1;
                }
            }
        }
    }
    __syncthreads();
    for (int t = threadIdx.x; t < B; t += 256) {
        int c = lcnt[t];
        lbase[t] = c ? atomicAdd(&bcnt[t], c) : 0;
    }
    __syncthreads();
#pragma unroll
    for (int r = 0; r < 16; ++r) {
        if (bk[r] >= 0) {
            int pos = lbase[bk[r]] + rk[r];
            if (pos < CAP) ebuf[((size_t)bk[r] << CAPSH) + pos] = pk[r];
        }
    }
}

// ---- pass B: per-bucket sort with rank capture -> deg/rowStart/dinv/srcSorted
// + vectorized y16 prep ----
__global__ __launch_bounds__(256) void passB(const int* __restrict__ ebuf,
                                             const int* __restrict__ bcnt,
                                             const float* __restrict__ x,
                                             int* __restrict__ rowStart,
                                             int* __restrict__ deg,
                                             float* __restrict__ dinv,
                                             int* __restrict__ srcSorted,
                                             __half* __restrict__ y, int N) {
    __shared__ int cnt[GSZ], inc[GSZ], exo[GSZ];
    __shared__ float ldinv[GSZ];
    int b = blockIdx.x, t = threadIdx.x;
    int m = min(bcnt[b], CAP);
    const int* eb = ebuf + ((size_t)b << CAPSH);
    if (t < GSZ) cnt[t] = 0;
    __syncthreads();
    int gk[16], sk[16], rk[16];
    int iters = (m + 255) >> 8;   // <= 16
    for (int it = 0; it < iters; ++it) {
        int i = t + (it << 8);
        if (i < m) {
            int pkv = eb[i];
            gk[it] = pkv >> 17;
            sk[it] = pkv & 0x1FFFF;
            rk[it] = atomicAdd(&cnt[gk[it]], 1);
        } else {
            gk[it] = -1;
        }
    }
    __syncthreads();
    int myc = (t < GSZ) ? cnt[t] : 0;
    if (t < GSZ) inc[t] = myc;
    __syncthreads();
    for (int o = 1; o < GSZ; o <<= 1) {
        int v = (t < GSZ && t >= o) ? inc[t - o] : 0;
        __syncthreads();
        if (t < GSZ) inc[t] += v;
        __syncthreads();
    }
    if (t < GSZ) {
        int ex = inc[t] - myc;
        exo[t] = ex;
        float di = rsqrtf((float)myc + 1.0f);
        ldinv[t] = di;
        int node = (b << GSH) + t;
        if (node < N) {
            rowStart[node] = (b << CAPSH) + ex;
            deg[node] = myc;
            dinv[node] = di;
        }
    }
    __syncthreads();
    int s0b = b << CAPSH;
    for (int it = 0; it < iters; ++it) {
        if (gk[it] >= 0)
            srcSorted[s0b + exo[gk[it]] + rk[it]] = sk[it];
    }
    // y16[n][k] = half(dinv[n]*x[n][k]), rows padded to 64; 4 halves/thread-step
    int nodeBase = b << GSH;
    for (int q = t; q < GSZ * 16; q += 256) {
        int nl = q >> 4, k4 = (q & 15) << 2;
        int node = nodeBase + nl;
        if (node < N) {
            ushort4 hv;
            if (k4 < F_IN) {
                float di = ldinv[nl];
                float4 xv = *(const float4*)(x + (size_t)node * F_IN + k4);
                hv.x = __half_as_ushort(__float2half(di * xv.x));
                hv.y = __half_as_ushort(__float2half(di * xv.y));
                hv.z = __half_as_ushort(__float2half(di * xv.z));
                hv.w = __half_as_ushort(__float2half(di * xv.w));
            } else {
                hv.x = hv.y = hv.z = hv.w = 0;
            }
            *(ushort4*)((char*)y + ((size_t)node << 7) + ((size_t)k4 << 1)) = hv;
        }
    }
}

// ---- fused: 4 nodes/wave, 48 gathers in flight (32-bit saddr offsets),
// readlane GEMM epilogue ----
__global__ __launch_bounds__(256) void fused1(const __half* __restrict__ y,
                                              const float* __restrict__ W1,
                                              const float* __restrict__ b1,
                                              const float* __restrict__ W2,
                                              const float* __restrict__ dinv,
                                              const int* __restrict__ rowStart,
                                              const int* __restrict__ deg,
                                              const int* __restrict__ srcSorted,
                                              float* __restrict__ g2, int N) {
    const int lane = threadIdx.x & 63;
    const int sub = lane >> 5;
    const int fl = lane & 31;
    const int base = blockIdx.x * 16 + (threadIdx.x >> 6) * 4;
    const char* yb = (const char*)y;
    const unsigned fb = (unsigned)fl << 2;

    int n0 = base, n1 = base + 1, n2 = base + 2, n3 = base + 3;
    int dn0 = (n0 < N) ? deg[n0] : -1;
    int dn1 = (n1 < N) ? deg[n1] : -1;
    int dn2_ = (n2 < N) ? deg[n2] : -1;
    int dn3 = (n3 < N) ? deg[n3] : -1;
    int rs0 = (n0 < N) ? rowStart[n0] : 0;
    int rs1 = (n1 < N) ? rowStart[n1] : 0;
    int rs2 = (n2 < N) ? rowStart[n2] : 0;
    int rs3 = (n3 < N) ? rowStart[n3] : 0;

    // slot map per lane: [0,dn)=edges, dn=self, rest=zero row N
    int idx0 = N, idx1 = N, idx2 = N, idx3 = N;
    if (lane < dn0) idx0 = srcSorted[rs0 + lane]; else if (lane == dn0) idx0 = n0;
    if (lane < dn1) idx1 = srcSorted[rs1 + lane]; else if (lane == dn1) idx1 = n1;
    if (lane < dn2_) idx2 = srcSorted[rs2 + lane]; else if (lane == dn2_) idx2 = n2;
    if (lane < dn3) idx3 = srcSorted[rs3 + lane]; else if (lane == dn3) idx3 = n3;

    float ax0 = 0, ay0 = 0, ax1 = 0, ay1 = 0;
    float ax2 = 0, ay2 = 0, ax3 = 0, ay3 = 0;

    auto step = [&](int p) {
        int sA = 2 * p + sub;
        unsigned o0 = ((unsigned)__shfl(idx0, sA, 64) << 7) + fb;
        unsigned o1 = ((unsigned)__shfl(idx1, sA, 64) << 7) + fb;
        unsigned o2 = ((unsigned)__shfl(idx2, sA, 64) << 7) + fb;
        unsigned o3 = ((unsigned)__shfl(idx3, sA, 64) << 7) + fb;
        float2 f0 = __half22float2(*(const __half2*)(yb + o0));
        float2 f1 = __half22float2(*(const __half2*)(yb + o1));
        float2 f2 = __half22float2(*(const __half2*)(yb + o2));
        float2 f3 = __half22float2(*(const __half2*)(yb + o3));
        ax0 += f0.x; ay0 += f0.y;
        ax1 += f1.x; ay1 += f1.y;
        ax2 += f2.x; ay2 += f2.y;
        ax3 += f3.x; ay3 += f3.y;
    };
#pragma unroll
    for (int p = 0; p < 12; ++p) step(p);   // 48 independent gathers in flight
    int maxSlot = max(max(dn0, dn1), max(dn2_, dn3)) + 1;
    for (int p = 12; p < 32 && 2 * p < maxSlot; ++p) step(p);  // rare
    if (maxSlot > 64) {  // astronomically rare
        const __half2* yp = (const __half2*)y;
        for (int s = 64; s < maxSlot; ++s) {
            if (sub == 0) {
                if (s <= dn0) { float2 f = __half22float2(yp[((long)((s < dn0) ? srcSorted[rs0 + s] : n0) << 5) + fl]); ax0 += f.x; ay0 += f.y; }
                if (s <= dn1) { float2 f = __half22float2(yp[((long)((s < dn1) ? srcSorted[rs1 + s] : n1) << 5) + fl]); ax1 += f.x; ay1 += f.y; }
                if (s <= dn2_) { float2 f = __half22float2(yp[((long)((s < dn2_) ? srcSorted[rs2 + s] : n2) << 5) + fl]); ax2 += f.x; ay2 += f.y; }
                if (s <= dn3) { float2 f = __half22float2(yp[((long)((s < dn3) ? srcSorted[rs3 + s] : n3) << 5) + fl]); ax3 += f.x; ay3 += f.y; }
            }
        }
    }

    // combine half-waves: lanes then hold v[2*fl], v[2*fl+1]
    ax0 += __shfl(ax0, lane ^ 32, 64); ay0 += __shfl(ay0, lane ^ 32, 64);
    ax1 += __shfl(ax1, lane ^ 32, 64); ay1 += __shfl(ay1, lane ^ 32, 64);
    ax2 += __shfl(ax2, lane ^ 32, 64); ay2 += __shfl(ay2, lane ^ 32, 64);
    ax3 += __shfl(ax3, lane ^ 32, 64); ay3 += __shfl(ay3, lane ^ 32, 64);
    float di0 = (n0 < N) ? dinv[n0] : 0.0f;
    float di1 = (n1 < N) ? dinv[n1] : 0.0f;
    float di2 = (n2 < N) ? dinv[n2] : 0.0f;
    float di3 = (n3 < N) ? dinv[n3] : 0.0f;
    ax0 *= di0; ay0 *= di0; ax1 *= di1; ay1 *= di1;
    ax2 *= di2; ay2 *= di2; ax3 *= di3; ay3 *= di3;

    float h0 = b1[lane], h1 = h0, h2 = h0, h3 = h0;
#pragma unroll
    for (int k = 0; k < F_IN; k += 2) {
        float wA = W1[k * F_HID + lane];
        float wB = W1[(k + 1) * F_HID + lane];
        const int q = k >> 1;
        h0 = fmaf(rdlane(ax0, q), wA, h0); h0 = fmaf(rdlane(ay0, q), wB, h0);
        h1 = fmaf(rdlane(ax1, q), wA, h1); h1 = fmaf(rdlane(ay1, q), wB, h1);
        h2 = fmaf(rdlane(ax2, q), wA, h2); h2 = fmaf(rdlane(ay2, q), wB, h2);
        h3 = fmaf(rdlane(ax3, q), wA, h3); h3 = fmaf(rdlane(ay3, q), wB, h3);
    }
    h0 = fmaxf(h0, 0.0f); h1 = fmaxf(h1, 0.0f);
    h2 = fmaxf(h2, 0.0f); h3 = fmaxf(h3, 0.0f);

    float2 w2 = ((const float2*)W2)[lane];
    float t00 = h0 * w2.x, t01 = h0 * w2.y;
    float t10 = h1 * w2.x, t11 = h1 * w2.y;
    float t20 = h2 * w2.x, t21 = h2 * w2.y;
    float t30 = h3 * w2.x, t31 = h3 * w2.y;
#pragma unroll
    for (int off = 32; off > 0; off >>= 1) {
        t00 += __shfl_down(t00, off, 64); t01 += __shfl_down(t01, off, 64);
        t10 += __shfl_down(t10, off, 64); t11 += __shfl_down(t11, off, 64);
        t20 += __shfl_down(t20, off, 64); t21 += __shfl_down(t21, off, 64);
        t30 += __shfl_down(t30, off, 64); t31 += __shfl_down(t31, off, 64);
    }
    if (lane == 0) {
        float2* g2v = (float2*)g2;
        if (n0 < N) g2v[n0] = make_float2(di0 * t00, di0 * t01);
        if (n1 < N) g2v[n1] = make_float2(di1 * t10, di1 * t11);
        if (n2 < N) g2v[n2] = make_float2(di2 * t20, di2 * t21);
        if (n3 < N) g2v[n3] = make_float2(di3 * t30, di3 * t31);
    }
}

// ---- layer-2 aggregation: 16 lanes per node, 32-bit offsets ----
__global__ __launch_bounds__(256) void agg2(const int* __restrict__ rowStart,
                                            const int* __restrict__ deg,
                                            const int* __restrict__ srcSorted,
                                            const float* __restrict__ g2,
                                            const float* __restrict__ dinv,
                                            const float* __restrict__ b2,
                                            float* __restrict__ out, int N) {
    int gid = blockIdx.x * 256 + threadIdx.x;
    int node = gid >> 4, l16 = gid & 15;
    if (node >= N) return;
    const char* gb = (const char*)g2;
    int rs = rowStart[node], dn = deg[node];
    float a0 = 0.0f, a1 = 0.0f;
    for (int j = l16; j < dn; j += 16) {
        unsigned o = (unsigned)srcSorted[rs + j] << 3;
        float2 v = *(const float2*)(gb + o);
        a0 += v.x;
        a1 += v.y;
    }
#pragma unroll
    for (int m = 1; m < 16; m <<= 1) {
        a0 += __shfl_xor(a0, m, 64);
        a1 += __shfl_xor(a1, m, 64);
    }
    if (l16 == 0) {
        float2 self = *(const float2*)(gb + ((unsigned)node << 3));
        float di = dinv[node];
        out[2 * node + 0] = di * (a0 + self.x) + b2[0];
        out[2 * node + 1] = di * (a1 + self.y) + b2[1];
    }
}

extern "C" void kernel_launch(void* const* d_in, const int* in_sizes, int n_in,
                              void* d_out, int out_size, void* d_ws, size_t ws_size,
                              hipStream_t stream) {
    const float* x  = (const float*)d_in[0];
    const int* eidx = (const int*)d_in[1];
    const float* W1 = (const float*)d_in[2];
    const float* b1 = (const float*)d_in[3];
    const float* W2 = (const float*)d_in[4];
    const float* b2 = (const float*)d_in[5];
    float* out = (float*)d_out;

    int N = in_sizes[0] / F_IN;   // 100000
    int E = in_sizes[1] / 2;      // 1600000
    int B = (N + GSZ - 1) >> GSH; // 782 buckets (<= MAXB)

    // layout: y16 rows 0..N (row N = zero row), then bcnt — adjacent so one
    // memset clears both (row N is 128 B; bcnt is MAXB*4 B).
    char* ws = (char*)d_ws;
    __half* y16       = (__half*)ws;   ws += (size_t)(N + 1) * 64 * 2;
    int*    bcnt      = (int*)ws;      ws += MAXB * 4;
    int*    deg       = (int*)ws;      ws += (size_t)N * 4;
    int*    rowStart  = (int*)ws;      ws += (size_t)N * 4;
    float*  dinv      = (float*)ws;    ws += (size_t)N * 4;
    float*  g2        = (float*)ws;    ws += (size_t)N * 2 * 4;
    ws = (char*)(((size_t)ws + 255) & ~(size_t)255);
    int*    ebuf      = (int*)ws;      ws += (size_t)MAXB * CAP * 4;
    int*    srcSorted = (int*)ws;      ws += (size_t)MAXB * CAP * 4;

    hipMemsetAsync(y16 + (size_t)N * 64, 0, 128 + MAXB * 4, stream);

    passA<<<(E + CHUNK - 1) / CHUNK, 256, 0, stream>>>(eidx, bcnt, ebuf, E, B);
    passB<<<B, 256, 0, stream>>>(ebuf, bcnt, x, rowStart, deg, dinv, srcSorted,
                                 y16, N);
    fused1<<<(N + 15) / 16, 256, 0, stream>>>(y16, W1, b1, W2, dinv, rowStart, deg,
                                              srcSorted, g2, N);
    agg2<<<(N * 16 + 255) / 256, 256, 0, stream>>>(rowStart, deg, srcSorted, g2,
                                                   dinv, b2, out, N);
}